// Round 8
// baseline (543.157 us; speedup 1.0000x reference)
//
#include <hip/hip_runtime.h>
#include <hip/hip_bf16.h>

#define DD 512
#define HDIM 64
#define NROWS 131072

typedef __bf16 bf16x8 __attribute__((ext_vector_type(8)));
typedef float f32x4 __attribute__((ext_vector_type(4)));

static __device__ __forceinline__ unsigned bfbits(float f) {
    union { float f; unsigned u; } x; x.f = f;
    unsigned r = x.u + 0x7fffu + ((x.u >> 16) & 1u);
    return r >> 16;
}
static __device__ __forceinline__ __bf16 to_bf16(float f) {
    union { unsigned short s; __bf16 b; } y; y.s = (unsigned short)bfbits(f); return y.b;
}

// Fragment-linear byte offset for a [512 cols][512 k] bf16 weight matrix:
// tile (c>>6, k>>5, (c>>4)&3) of 1024B; within: lane=(k>>3 grp)*16+(c&15), elem k&7.
// A wave's frag load = base + (c64*64 + kt*4 + n)*1024 + lane*16  (fully coalesced).
static __device__ __forceinline__ size_t fragoff(int c, int d) {
    return (size_t)((((c >> 6) * 64 + (d >> 5) * 4 + ((c >> 4) & 3)) << 10)
         + (((((d >> 3) & 3) << 4) + (c & 15)) << 4) + ((d & 7) << 1));
}

static __device__ __forceinline__ void gll16(const void* gsrc, void* ldst) {
    __builtin_amdgcn_global_load_lds(
        (const __attribute__((address_space(1))) unsigned int*)gsrc,
        (__attribute__((address_space(3))) unsigned int*)ldst, 16, 0, 0);
}

#define VMCNT(n) asm volatile("s_waitcnt vmcnt(" #n ")" ::: "memory")

// bijective XCD-chunk swizzle (m204)
static __device__ __forceinline__ int xcd_swz(int bid, int nwg) {
    const int q = nwg >> 3, r = nwg & 7;
    const int xcd = bid & 7, idx = bid >> 3;
    return (xcd < r ? xcd * (q + 1) : r * (q + 1) + (xcd - r) * q) + idx;
}

// ---------------- prep 1: k/v projections of memory (tiny) ----------------
__global__ void prep_kv(const float* __restrict__ memory,
                        const float* __restrict__ Wk, const float* __restrict__ bk,
                        const float* __restrict__ Wv, const float* __restrict__ bv,
                        float* __restrict__ kproj, float* __restrict__ vproj) {
    __shared__ float mrow[DD];
    const int m = blockIdx.x;
    const int t = threadIdx.x;
    for (int i = t; i < DD; i += 256) mrow[i] = memory[(size_t)m * DD + i];
    __syncthreads();
    for (int jj = 0; jj < 2; ++jj) {
        const int j = t + jj * 256;
        const float* wkr = Wk + (size_t)j * DD;
        const float* wvr = Wv + (size_t)j * DD;
        float sk = 0.f, sv = 0.f;
        for (int d = 0; d < DD; ++d) {
            const float md = mrow[d];
            sk += md * wkr[d];
            sv += md * wvr[d];
        }
        kproj[(size_t)m * DD + j] = sk + bk[j];
        vproj[(size_t)m * DD + j] = sv + bv[j];
    }
}

// ---------------- prep 2: fold into W2fr / b2 / W3fr (fragment-linear) -------
__global__ void prep_w(const float* __restrict__ Wq, const float* __restrict__ bq,
                       const float* __restrict__ Wo,
                       const float* __restrict__ kproj, const float* __restrict__ vproj,
                       __bf16* __restrict__ W2fr, float* __restrict__ b2,
                       __bf16* __restrict__ W3fr) {
    const int i = blockIdx.x;   // c (score-col) for W2fr/b2; j (out-col) for W3fr
    const int t = threadIdx.x;
    __shared__ float kp[HDIM];
    __shared__ float worow[DD];
    const int m = i & 63, h = i >> 6;
    if (t < HDIM) kp[t] = kproj[(size_t)m * DD + h * HDIM + t];
    for (int d = t; d < DD; d += 256) worow[d] = Wo[(size_t)i * DD + d];
    __syncthreads();
    for (int dd2 = 0; dd2 < 2; ++dd2) {
        const int d = t + dd2 * 256;
        float s = 0.f;
        #pragma unroll 8
        for (int hd = 0; hd < HDIM; ++hd)
            s += Wq[(size_t)(h * HDIM + hd) * DD + d] * kp[hd];
        *(__bf16*)((char*)W2fr + fragoff(i, d)) = to_bf16(s);
    }
    if (t == 0) {
        float s = 0.f;
        for (int hd = 0; hd < HDIM; ++hd) s += bq[h * HDIM + hd] * kp[hd];
        b2[i] = s;
    }
    for (int cc = 0; cc < 2; ++cc) {
        const int c = t + cc * 256;
        const int mc = c & 63, hc = c >> 6;
        float s = 0.f;
        #pragma unroll 8
        for (int hd = 0; hd < HDIM; ++hd)
            s += vproj[(size_t)mc * DD + hc * HDIM + hd] * worow[hc * HDIM + hd];
        *(__bf16*)((char*)W3fr + fragoff(i, c)) = to_bf16(s);
    }
}

// ---------------- kernel 1: S = x@W2 + b2, softmax -> attn_p (frag order) -----
// Block: 128 rows x 2 heads; 4 waves (wr=row-half, wh=head). LDS = A dbuf only.
// B frags stream reg-dbuf'd from fragment-linear W2fr (coalesced).
__global__ __launch_bounds__(256, 4) void k1_gemm_sm(
    const float* __restrict__ x, const int* __restrict__ mask,
    const __bf16* __restrict__ W2fr, const float* __restrict__ b2,
    __bf16* __restrict__ attn_p, int row0) {
    __shared__ char ldsb[32768];   // A fp32 dbuf: 0 / 16384

    const int tid = threadIdx.x;
    const int lane = tid & 63;
    const int wid = tid >> 6;
    const int wr = wid >> 1, wh = wid & 1;
    const int lc = lane & 15, grp = lane >> 4;
    const int swz = xcd_swz(blockIdx.x, gridDim.x);
    const int nt2 = swz & 3, rt = swz >> 2;
    const int rl0 = rt * 128;
    const int gr0 = row0 + rl0;
    const int h = nt2 * 2 + wh;

    const char* bbase = (const char*)W2fr + ((size_t)h * 64) * 1024 + lane * 16;

    // A-gll per-lane source (inverse of the fp32 bank swizzle)
    const float* psA[4];
    #pragma unroll
    for (int i = 0; i < 4; ++i) {
        const int G = i * 256 + tid;
        const int rowA = G >> 3;
        const int gA = (G & 7) ^ (rowA & 7);
        psA[i] = x + (size_t)(gr0 + rowA) * DD + gA * 4;
    }

    #define STAGEA(kt, buf)                                                        \
        { _Pragma("unroll")                                                        \
          for (int i = 0; i < 4; ++i)                                              \
              gll16(psA[i] + (kt) * 32, ldsb + (buf) * 16384 + i * 4096 + wid * 1024); }
    #define LOADB1(kt, buf)                                                        \
        { _Pragma("unroll")                                                        \
          for (int n = 0; n < 4; ++n)                                              \
              bb[buf][n] = *(const bf16x8*)(bbase + ((kt) * 4 + n) * 1024); }

    bf16x8 bb[2][4];
    f32x4 acc[4][4];
    #pragma unroll
    for (int m = 0; m < 4; ++m)
        #pragma unroll
        for (int n = 0; n < 4; ++n) acc[m][n] = (f32x4){0.f, 0.f, 0.f, 0.f};

    STAGEA(0, 0);
    LOADB1(0, 0);

    #pragma unroll
    for (int kt = 0; kt < 16; ++kt) {
        const int p = kt & 1;
        if (kt < 15) {
            STAGEA(kt + 1, p ^ 1);
            LOADB1(kt + 1, p ^ 1);
            VMCNT(8);
        } else {
            VMCNT(0);
        }
        __builtin_amdgcn_s_barrier();
        bf16x8 af[4];
        #pragma unroll
        for (int m = 0; m < 4; ++m) {
            const int row = wr * 64 + m * 16 + lc;
            const char* base = ldsb + p * 16384 + row * 128;
            const f32x4 lo = *(const f32x4*)(base + (((grp * 2) ^ (row & 7)) * 16));
            const f32x4 hi = *(const f32x4*)(base + (((grp * 2 + 1) ^ (row & 7)) * 16));
            bf16x8 v;
            v[0] = (__bf16)lo[0]; v[1] = (__bf16)lo[1]; v[2] = (__bf16)lo[2]; v[3] = (__bf16)lo[3];
            v[4] = (__bf16)hi[0]; v[5] = (__bf16)hi[1]; v[6] = (__bf16)hi[2]; v[7] = (__bf16)hi[3];
            af[m] = v;
        }
        __builtin_amdgcn_s_setprio(1);
        #pragma unroll
        for (int m = 0; m < 4; ++m)
            #pragma unroll
            for (int n = 0; n < 4; ++n)
                acc[m][n] = __builtin_amdgcn_mfma_f32_16x16x32_bf16(af[m], bb[p][n], acc[m][n], 0, 0, 0);
        __builtin_amdgcn_s_setprio(0);
        __builtin_amdgcn_s_barrier();
    }
    #undef STAGEA
    #undef LOADB1

    // ---- softmax (wave-local head) + frag-order repack via wave-private LDS
    float b2v[4];
    #pragma unroll
    for (int n = 0; n < 4; ++n) b2v[n] = b2[h * 64 + n * 16 + lc];

    char* wslab = ldsb + wid * 8192;   // 2 k-slabs x 4 tiles x 1024B
    #pragma unroll
    for (int m = 0; m < 4; ++m) {
        const int lr = m * 16 + grp * 4;
        const int4 mv = *(const int4*)(mask + gr0 + wr * 64 + lr);
        const int mk[4] = {mv.x, mv.y, mv.z, mv.w};
        #pragma unroll
        for (int j = 0; j < 4; ++j) {
            float s0 = (acc[m][0][j] + b2v[0]) * 0.125f;
            float s1 = (acc[m][1][j] + b2v[1]) * 0.125f;
            float s2 = (acc[m][2][j] + b2v[2]) * 0.125f;
            float s3 = (acc[m][3][j] + b2v[3]) * 0.125f;
            float mx = fmaxf(fmaxf(s0, s1), fmaxf(s2, s3));
            mx = fmaxf(mx, __shfl_xor(mx, 1));
            mx = fmaxf(mx, __shfl_xor(mx, 2));
            mx = fmaxf(mx, __shfl_xor(mx, 4));
            mx = fmaxf(mx, __shfl_xor(mx, 8));
            float p0 = __expf(s0 - mx);
            float p1 = __expf(s1 - mx);
            float p2 = __expf(s2 - mx);
            float p3 = __expf(s3 - mx);
            float sm = (p0 + p1) + (p2 + p3);
            sm += __shfl_xor(sm, 1);
            sm += __shfl_xor(sm, 2);
            sm += __shfl_xor(sm, 4);
            sm += __shfl_xor(sm, 8);
            float a[4];
            if (mk[j] == 0) {
                a[0] = a[1] = a[2] = a[3] = 0.015625f;  // fp32 -1e9 bias -> uniform attn
            } else {
                const float inv = 1.0f / sm;
                a[0] = p0 * inv; a[1] = p1 * inv; a[2] = p2 * inv; a[3] = p3 * inv;
            }
            #pragma unroll
            for (int n = 0; n < 4; ++n) {
                const int off = (((n >> 1) * 4 + m) << 10)
                              + (((((n & 1) * 2 + (lc >> 3)) << 4) + (grp * 4 + j)) << 4)
                              + ((lc & 7) << 1);
                *(short*)(wslab + off) = (short)bfbits(a[n]);
            }
        }
    }
    // coalesced copy-out: frag-linear global layout
    char* ablk = (char*)attn_p + (size_t)rt * 131072;
    #pragma unroll
    for (int s = 0; s < 2; ++s) {
        #pragma unroll
        for (int m = 0; m < 4; ++m) {
            bf16x8 v = *(const bf16x8*)(wslab + (s * 4 + m) * 1024 + lane * 16);
            *(bf16x8*)(ablk + ((h * 2 + s) * 8 + wr * 4 + m) * 1024 + lane * 16) = v;
        }
    }
}

// ---------------- kernel 2: out = attn@W3 + bo (no LDS, no barriers) ----------
__global__ __launch_bounds__(256, 3) void k2_gemm_out(
    const __bf16* __restrict__ attn_p, const __bf16* __restrict__ W3fr,
    const float* __restrict__ bo, float* __restrict__ out, int row0) {
    const int tid = threadIdx.x;
    const int lane = tid & 63;
    const int wid = tid >> 6;
    const int wr = wid >> 1, wc = wid & 1;
    const int lc = lane & 15, grp = lane >> 4;
    const int swz = xcd_swz(blockIdx.x, gridDim.x);
    const int nt = swz & 3, rt = swz >> 2;
    const int c0 = nt * 128 + wc * 64;

    const char* abase = (const char*)attn_p + (size_t)rt * 131072 + (wr * 4) * 1024 + lane * 16;
    const char* bbase = (const char*)W3fr + ((size_t)(c0 >> 6) * 64) * 1024 + lane * 16;

    #define LA2(kt, buf)                                                           \
        { _Pragma("unroll")                                                        \
          for (int m = 0; m < 4; ++m)                                              \
              aa[buf][m] = *(const bf16x8*)(abase + ((kt) * 8 + m) * 1024); }
    #define LB2(kt, buf)                                                           \
        { _Pragma("unroll")                                                        \
          for (int n = 0; n < 4; ++n)                                              \
              bb[buf][n] = *(const bf16x8*)(bbase + ((kt) * 4 + n) * 1024); }

    bf16x8 aa[2][4], bb[2][4];
    f32x4 acc[4][4];
    #pragma unroll
    for (int m = 0; m < 4; ++m)
        #pragma unroll
        for (int n = 0; n < 4; ++n) acc[m][n] = (f32x4){0.f, 0.f, 0.f, 0.f};

    LA2(0, 0);
    LB2(0, 0);

    #pragma unroll
    for (int kt = 0; kt < 16; ++kt) {
        const int p = kt & 1;
        if (kt < 15) {
            LA2(kt + 1, p ^ 1);
            LB2(kt + 1, p ^ 1);
        }
        __builtin_amdgcn_s_setprio(1);
        #pragma unroll
        for (int m = 0; m < 4; ++m)
            #pragma unroll
            for (int n = 0; n < 4; ++n)
                acc[m][n] = __builtin_amdgcn_mfma_f32_16x16x32_bf16(aa[p][m], bb[p][n], acc[m][n], 0, 0, 0);
        __builtin_amdgcn_s_setprio(0);
    }
    #undef LA2
    #undef LB2

    float bov[4];
    #pragma unroll
    for (int n = 0; n < 4; ++n) bov[n] = bo[c0 + n * 16 + lc];

    #pragma unroll
    for (int m = 0; m < 4; ++m) {
        #pragma unroll
        for (int j = 0; j < 4; ++j) {
            const int gr = row0 + rt * 128 + wr * 64 + m * 16 + grp * 4 + j;
            float* orow = out + (size_t)gr * DD + c0 + lc;
            #pragma unroll
            for (int n = 0; n < 4; ++n)
                __builtin_nontemporal_store(acc[m][n][j] + bov[n], orow + n * 16);
        }
    }
}

extern "C" void kernel_launch(void* const* d_in, const int* in_sizes, int n_in,
                              void* d_out, int out_size, void* d_ws, size_t ws_size,
                              hipStream_t stream) {
    const float* qf     = (const float*)d_in[0];
    const int*   mask   = (const int*)d_in[1];
    const float* memory = (const float*)d_in[2];
    const float* Wq     = (const float*)d_in[3];
    const float* bq     = (const float*)d_in[4];
    const float* Wk     = (const float*)d_in[5];
    const float* bk     = (const float*)d_in[6];
    const float* Wv     = (const float*)d_in[7];
    const float* bv     = (const float*)d_in[8];
    const float* Wo     = (const float*)d_in[9];
    const float* bo     = (const float*)d_in[10];

    char* ws = (char*)d_ws;
    float*  kproj = (float*)ws;                  // 128 KB
    float*  vproj = (float*)(ws + 131072);       // 128 KB
    float*  b2    = (float*)(ws + 262144);       // 2 KB
    __bf16* W2fr  = (__bf16*)(ws + 264192);      // 512 KB
    __bf16* W3fr  = (__bf16*)(ws + 788480);      // 512 KB
    __bf16* attn_p= (__bf16*)(ws + 1572864);     // frag-order intermediate

    size_t avail = ws_size > 1572864 ? ws_size - 1572864 : 0;
    long mr = (long)(avail / 1024);              // 1024 B per row
    int rpc = (int)((mr / 128) * 128);
    if (rpc > NROWS) rpc = NROWS;
    if (rpc < 128) rpc = 128;

    prep_kv<<<64, 256, 0, stream>>>(memory, Wk, bk, Wv, bv, kproj, vproj);
    prep_w<<<512, 256, 0, stream>>>(Wq, bq, Wo, kproj, vproj, W2fr, b2, W3fr);

    for (int row0 = 0; row0 < NROWS; row0 += rpc) {
        int rows = NROWS - row0; if (rows > rpc) rows = rpc;
        const int nwg = (rows / 128) * 4;
        k1_gemm_sm<<<nwg, 256, 0, stream>>>(qf, mask, W2fr, b2, attn_p, row0);
        k2_gemm_out<<<nwg, 256, 0, stream>>>(attn_p, W3fr, bo, (float*)d_out, row0);
    }
}

// Round 9
// 356.437 us; speedup vs baseline: 1.5238x; 1.5238x over previous
//
#include <hip/hip_runtime.h>
#include <hip/hip_bf16.h>

#define DD 512
#define HDIM 64
#define NROWS 131072

typedef __bf16 bf16x8 __attribute__((ext_vector_type(8)));
typedef float f32x4 __attribute__((ext_vector_type(4)));

static __device__ __forceinline__ unsigned bfbits(float f) {
    union { float f; unsigned u; } x; x.f = f;
    unsigned r = x.u + 0x7fffu + ((x.u >> 16) & 1u);
    return r >> 16;
}
static __device__ __forceinline__ __bf16 to_bf16(float f) {
    union { unsigned short s; __bf16 b; } y; y.s = (unsigned short)bfbits(f); return y.b;
}

// Fragment-linear byte offset for a [512 cols][512 k] bf16 weight matrix:
// tile (c>>6, k>>5, (c>>4)&3) of 1024B; within: lane=(k>>3 grp)*16+(c&15), elem k&7.
// A wave's frag load = base + (c64*64 + kt*4 + n)*1024 + lane*16  (fully coalesced).
static __device__ __forceinline__ size_t fragoff(int c, int d) {
    return (size_t)((((c >> 6) * 64 + (d >> 5) * 4 + ((c >> 4) & 3)) << 10)
         + (((((d >> 3) & 3) << 4) + (c & 15)) << 4) + ((d & 7) << 1));
}

static __device__ __forceinline__ void gll16(const void* gsrc, void* ldst) {
    __builtin_amdgcn_global_load_lds(
        (const __attribute__((address_space(1))) unsigned int*)gsrc,
        (__attribute__((address_space(3))) unsigned int*)ldst, 16, 0, 0);
}

#define VMCNT(n) asm volatile("s_waitcnt vmcnt(" #n ")" ::: "memory")

// bijective XCD-chunk swizzle (m204)
static __device__ __forceinline__ int xcd_swz(int bid, int nwg) {
    const int q = nwg >> 3, r = nwg & 7;
    const int xcd = bid & 7, idx = bid >> 3;
    return (xcd < r ? xcd * (q + 1) : r * (q + 1) + (xcd - r) * q) + idx;
}

// ---------------- prep 1: k/v projections of memory (tiny) ----------------
__global__ void prep_kv(const float* __restrict__ memory,
                        const float* __restrict__ Wk, const float* __restrict__ bk,
                        const float* __restrict__ Wv, const float* __restrict__ bv,
                        float* __restrict__ kproj, float* __restrict__ vproj) {
    __shared__ float mrow[DD];
    const int m = blockIdx.x;
    const int t = threadIdx.x;
    for (int i = t; i < DD; i += 256) mrow[i] = memory[(size_t)m * DD + i];
    __syncthreads();
    for (int jj = 0; jj < 2; ++jj) {
        const int j = t + jj * 256;
        const float* wkr = Wk + (size_t)j * DD;
        const float* wvr = Wv + (size_t)j * DD;
        float sk = 0.f, sv = 0.f;
        for (int d = 0; d < DD; ++d) {
            const float md = mrow[d];
            sk += md * wkr[d];
            sv += md * wvr[d];
        }
        kproj[(size_t)m * DD + j] = sk + bk[j];
        vproj[(size_t)m * DD + j] = sv + bv[j];
    }
}

// ---------------- prep 2: fold into W2fr / b2 / W3fr (fragment-linear) -------
__global__ void prep_w(const float* __restrict__ Wq, const float* __restrict__ bq,
                       const float* __restrict__ Wo,
                       const float* __restrict__ kproj, const float* __restrict__ vproj,
                       __bf16* __restrict__ W2fr, float* __restrict__ b2,
                       __bf16* __restrict__ W3fr) {
    const int i = blockIdx.x;   // c (score-col) for W2fr/b2; j (out-col) for W3fr
    const int t = threadIdx.x;
    __shared__ float kp[HDIM];
    __shared__ float worow[DD];
    const int m = i & 63, h = i >> 6;
    if (t < HDIM) kp[t] = kproj[(size_t)m * DD + h * HDIM + t];
    for (int d = t; d < DD; d += 256) worow[d] = Wo[(size_t)i * DD + d];
    __syncthreads();
    for (int dd2 = 0; dd2 < 2; ++dd2) {
        const int d = t + dd2 * 256;
        float s = 0.f;
        #pragma unroll 8
        for (int hd = 0; hd < HDIM; ++hd)
            s += Wq[(size_t)(h * HDIM + hd) * DD + d] * kp[hd];
        *(__bf16*)((char*)W2fr + fragoff(i, d)) = to_bf16(s);
    }
    if (t == 0) {
        float s = 0.f;
        for (int hd = 0; hd < HDIM; ++hd) s += bq[h * HDIM + hd] * kp[hd];
        b2[i] = s;
    }
    for (int cc = 0; cc < 2; ++cc) {
        const int c = t + cc * 256;
        const int mc = c & 63, hc = c >> 6;
        float s = 0.f;
        #pragma unroll 8
        for (int hd = 0; hd < HDIM; ++hd)
            s += vproj[(size_t)mc * DD + hc * HDIM + hd] * worow[hc * HDIM + hd];
        *(__bf16*)((char*)W3fr + fragoff(i, c)) = to_bf16(s);
    }
}

// ---------------- kernel 1: S = x@W2 + b2, softmax -> attn_p (frag order) -----
// Block: 128 rows x 2 heads; 4 waves (wr=row-half, wh=head). LDS = A dbuf only.
// B frags stream reg-dbuf'd from fragment-linear W2fr (coalesced).
// launch_bounds(256,3): 168 VGPR budget -> acc(64 AGPR) + regs fit, NO SPILL.
__global__ __launch_bounds__(256, 3) void k1_gemm_sm(
    const float* __restrict__ x, const int* __restrict__ mask,
    const __bf16* __restrict__ W2fr, const float* __restrict__ b2,
    __bf16* __restrict__ attn_p, int row0) {
    __shared__ char ldsb[32768];   // A fp32 dbuf: 0 / 16384

    const int tid = threadIdx.x;
    const int lane = tid & 63;
    const int wid = tid >> 6;
    const int wr = wid >> 1, wh = wid & 1;
    const int lc = lane & 15, grp = lane >> 4;
    const int swz = xcd_swz(blockIdx.x, gridDim.x);
    const int nt2 = swz & 3, rt = swz >> 2;
    const int rl0 = rt * 128;
    const int gr0 = row0 + rl0;
    const int h = nt2 * 2 + wh;

    const char* bbase = (const char*)W2fr + ((size_t)h * 64) * 1024 + lane * 16;

    // A-gll per-lane source (inverse of the fp32 bank swizzle)
    const float* psA[4];
    #pragma unroll
    for (int i = 0; i < 4; ++i) {
        const int G = i * 256 + tid;
        const int rowA = G >> 3;
        const int gA = (G & 7) ^ (rowA & 7);
        psA[i] = x + (size_t)(gr0 + rowA) * DD + gA * 4;
    }

    #define STAGEA(kt, buf)                                                        \
        { _Pragma("unroll")                                                        \
          for (int i = 0; i < 4; ++i)                                              \
              gll16(psA[i] + (kt) * 32, ldsb + (buf) * 16384 + i * 4096 + wid * 1024); }
    #define LOADB1(kt, buf)                                                        \
        { _Pragma("unroll")                                                        \
          for (int n = 0; n < 4; ++n)                                              \
              bb[buf][n] = *(const bf16x8*)(bbase + ((kt) * 4 + n) * 1024); }

    bf16x8 bb[2][4];
    f32x4 acc[4][4];
    #pragma unroll
    for (int m = 0; m < 4; ++m)
        #pragma unroll
        for (int n = 0; n < 4; ++n) acc[m][n] = (f32x4){0.f, 0.f, 0.f, 0.f};

    STAGEA(0, 0);
    LOADB1(0, 0);

    #pragma unroll
    for (int kt = 0; kt < 16; ++kt) {
        const int p = kt & 1;
        if (kt < 15) {
            STAGEA(kt + 1, p ^ 1);
            LOADB1(kt + 1, p ^ 1);
            VMCNT(8);
        } else {
            VMCNT(0);
        }
        __builtin_amdgcn_s_barrier();
        bf16x8 af[4];
        #pragma unroll
        for (int m = 0; m < 4; ++m) {
            const int row = wr * 64 + m * 16 + lc;
            const char* base = ldsb + p * 16384 + row * 128;
            const f32x4 lo = *(const f32x4*)(base + (((grp * 2) ^ (row & 7)) * 16));
            const f32x4 hi = *(const f32x4*)(base + (((grp * 2 + 1) ^ (row & 7)) * 16));
            bf16x8 v;
            v[0] = (__bf16)lo[0]; v[1] = (__bf16)lo[1]; v[2] = (__bf16)lo[2]; v[3] = (__bf16)lo[3];
            v[4] = (__bf16)hi[0]; v[5] = (__bf16)hi[1]; v[6] = (__bf16)hi[2]; v[7] = (__bf16)hi[3];
            af[m] = v;
        }
        __builtin_amdgcn_s_setprio(1);
        #pragma unroll
        for (int m = 0; m < 4; ++m)
            #pragma unroll
            for (int n = 0; n < 4; ++n)
                acc[m][n] = __builtin_amdgcn_mfma_f32_16x16x32_bf16(af[m], bb[p][n], acc[m][n], 0, 0, 0);
        __builtin_amdgcn_s_setprio(0);
        __builtin_amdgcn_s_barrier();
    }
    #undef STAGEA
    #undef LOADB1

    // ---- softmax (wave-local head) + frag-order repack via wave-private LDS
    float b2v[4];
    #pragma unroll
    for (int n = 0; n < 4; ++n) b2v[n] = b2[h * 64 + n * 16 + lc];

    char* wslab = ldsb + wid * 8192;   // 2 k-slabs x 4 tiles x 1024B
    #pragma unroll
    for (int m = 0; m < 4; ++m) {
        const int lr = m * 16 + grp * 4;
        const int4 mv = *(const int4*)(mask + gr0 + wr * 64 + lr);
        const int mk[4] = {mv.x, mv.y, mv.z, mv.w};
        #pragma unroll
        for (int j = 0; j < 4; ++j) {
            float s0 = (acc[m][0][j] + b2v[0]) * 0.125f;
            float s1 = (acc[m][1][j] + b2v[1]) * 0.125f;
            float s2 = (acc[m][2][j] + b2v[2]) * 0.125f;
            float s3 = (acc[m][3][j] + b2v[3]) * 0.125f;
            float mx = fmaxf(fmaxf(s0, s1), fmaxf(s2, s3));
            mx = fmaxf(mx, __shfl_xor(mx, 1));
            mx = fmaxf(mx, __shfl_xor(mx, 2));
            mx = fmaxf(mx, __shfl_xor(mx, 4));
            mx = fmaxf(mx, __shfl_xor(mx, 8));
            float p0 = __expf(s0 - mx);
            float p1 = __expf(s1 - mx);
            float p2 = __expf(s2 - mx);
            float p3 = __expf(s3 - mx);
            float sm = (p0 + p1) + (p2 + p3);
            sm += __shfl_xor(sm, 1);
            sm += __shfl_xor(sm, 2);
            sm += __shfl_xor(sm, 4);
            sm += __shfl_xor(sm, 8);
            float a[4];
            if (mk[j] == 0) {
                a[0] = a[1] = a[2] = a[3] = 0.015625f;  // fp32 -1e9 bias -> uniform attn
            } else {
                const float inv = 1.0f / sm;
                a[0] = p0 * inv; a[1] = p1 * inv; a[2] = p2 * inv; a[3] = p3 * inv;
            }
            #pragma unroll
            for (int n = 0; n < 4; ++n) {
                const int off = (((n >> 1) * 4 + m) << 10)
                              + (((((n & 1) * 2 + (lc >> 3)) << 4) + (grp * 4 + j)) << 4)
                              + ((lc & 7) << 1);
                *(short*)(wslab + off) = (short)bfbits(a[n]);
            }
        }
    }
    // coalesced copy-out: frag-linear global layout
    char* ablk = (char*)attn_p + (size_t)rt * 131072;
    #pragma unroll
    for (int s = 0; s < 2; ++s) {
        #pragma unroll
        for (int m = 0; m < 4; ++m) {
            bf16x8 v = *(const bf16x8*)(wslab + (s * 4 + m) * 1024 + lane * 16);
            *(bf16x8*)(ablk + ((h * 2 + s) * 8 + wr * 4 + m) * 1024 + lane * 16) = v;
        }
    }
}

// ---------------- kernel 2: out = attn@W3 + bo (no LDS, no barriers) ----------
__global__ __launch_bounds__(256, 3) void k2_gemm_out(
    const __bf16* __restrict__ attn_p, const __bf16* __restrict__ W3fr,
    const float* __restrict__ bo, float* __restrict__ out, int row0) {
    const int tid = threadIdx.x;
    const int lane = tid & 63;
    const int wid = tid >> 6;
    const int wr = wid >> 1, wc = wid & 1;
    const int lc = lane & 15, grp = lane >> 4;
    const int swz = xcd_swz(blockIdx.x, gridDim.x);
    const int nt = swz & 3, rt = swz >> 2;
    const int c0 = nt * 128 + wc * 64;

    const char* abase = (const char*)attn_p + (size_t)rt * 131072 + (wr * 4) * 1024 + lane * 16;
    const char* bbase = (const char*)W3fr + ((size_t)(c0 >> 6) * 64) * 1024 + lane * 16;

    #define LA2(kt, buf)                                                           \
        { _Pragma("unroll")                                                        \
          for (int m = 0; m < 4; ++m)                                              \
              aa[buf][m] = *(const bf16x8*)(abase + ((kt) * 8 + m) * 1024); }
    #define LB2(kt, buf)                                                           \
        { _Pragma("unroll")                                                        \
          for (int n = 0; n < 4; ++n)                                              \
              bb[buf][n] = *(const bf16x8*)(bbase + ((kt) * 4 + n) * 1024); }

    bf16x8 aa[2][4], bb[2][4];
    f32x4 acc[4][4];
    #pragma unroll
    for (int m = 0; m < 4; ++m)
        #pragma unroll
        for (int n = 0; n < 4; ++n) acc[m][n] = (f32x4){0.f, 0.f, 0.f, 0.f};

    LA2(0, 0);
    LB2(0, 0);

    #pragma unroll
    for (int kt = 0; kt < 16; ++kt) {
        const int p = kt & 1;
        if (kt < 15) {
            LA2(kt + 1, p ^ 1);
            LB2(kt + 1, p ^ 1);
        }
        __builtin_amdgcn_s_setprio(1);
        #pragma unroll
        for (int m = 0; m < 4; ++m)
            #pragma unroll
            for (int n = 0; n < 4; ++n)
                acc[m][n] = __builtin_amdgcn_mfma_f32_16x16x32_bf16(aa[p][m], bb[p][n], acc[m][n], 0, 0, 0);
        __builtin_amdgcn_s_setprio(0);
    }
    #undef LA2
    #undef LB2

    float bov[4];
    #pragma unroll
    for (int n = 0; n < 4; ++n) bov[n] = bo[c0 + n * 16 + lc];

    #pragma unroll
    for (int m = 0; m < 4; ++m) {
        #pragma unroll
        for (int j = 0; j < 4; ++j) {
            const int gr = row0 + rt * 128 + wr * 64 + m * 16 + grp * 4 + j;
            float* orow = out + (size_t)gr * DD + c0 + lc;
            #pragma unroll
            for (int n = 0; n < 4; ++n)
                __builtin_nontemporal_store(acc[m][n][j] + bov[n], orow + n * 16);
        }
    }
}

extern "C" void kernel_launch(void* const* d_in, const int* in_sizes, int n_in,
                              void* d_out, int out_size, void* d_ws, size_t ws_size,
                              hipStream_t stream) {
    const float* qf     = (const float*)d_in[0];
    const int*   mask   = (const int*)d_in[1];
    const float* memory = (const float*)d_in[2];
    const float* Wq     = (const float*)d_in[3];
    const float* bq     = (const float*)d_in[4];
    const float* Wk     = (const float*)d_in[5];
    const float* bk     = (const float*)d_in[6];
    const float* Wv     = (const float*)d_in[7];
    const float* bv     = (const float*)d_in[8];
    const float* Wo     = (const float*)d_in[9];
    const float* bo     = (const float*)d_in[10];

    char* ws = (char*)d_ws;
    float*  kproj = (float*)ws;                  // 128 KB
    float*  vproj = (float*)(ws + 131072);       // 128 KB
    float*  b2    = (float*)(ws + 262144);       // 2 KB
    __bf16* W2fr  = (__bf16*)(ws + 264192);      // 512 KB
    __bf16* W3fr  = (__bf16*)(ws + 788480);      // 512 KB
    __bf16* attn_p= (__bf16*)(ws + 1572864);     // frag-order intermediate

    size_t avail = ws_size > 1572864 ? ws_size - 1572864 : 0;
    long mr = (long)(avail / 1024);              // 1024 B per row
    int rpc = (int)((mr / 128) * 128);
    if (rpc > NROWS) rpc = NROWS;
    if (rpc < 128) rpc = 128;

    prep_kv<<<64, 256, 0, stream>>>(memory, Wk, bk, Wv, bv, kproj, vproj);
    prep_w<<<512, 256, 0, stream>>>(Wq, bq, Wo, kproj, vproj, W2fr, b2, W3fr);

    for (int row0 = 0; row0 < NROWS; row0 += rpc) {
        int rows = NROWS - row0; if (rows > rpc) rows = rpc;
        const int nwg = (rows / 128) * 4;
        k1_gemm_sm<<<nwg, 256, 0, stream>>>(qf, mask, W2fr, b2, attn_p, row0);
        k2_gemm_out<<<nwg, 256, 0, stream>>>(attn_p, W3fr, bo, (float*)d_out, row0);
    }
}